// Round 6
// baseline (215.296 us; speedup 1.0000x reference)
//
#include <hip/hip_runtime.h>
#include <hip/hip_fp16.h>
#include <math.h>

// FBP adjoint: out[b,i0,i1,i2] = (1/A) * sum_j lerp(x[b,j,i1,:], ix(j,i0,i2))
//   ix = 16 + (i2-16)*cos(a_j) + (i0-16)*sin(a_j); y-interp exact (iy==i1).
//
// R6 = R5 structure + deterministic packed inner loop + grid-stride tail fix.
//  - LDS dr[j][p] = uint( half(x[b0,j,i1,p-7]) | half(x[b1,j,i1,p-7])<<16 ),
//    zero-padded p in [0,47) => OOB corners contribute 0 (matches w*valid).
//  - Per (j,n): one ds_read2_b32 (dwords kp,kp+1) = 4 corner halves for both b.
//    v_perm_b32 x2 repacks into per-b (k,k+1) fp16 pairs; v_dot2_f32_f16 x2
//    does both lerps with fp32 accumulate. All explicit builtins -> no reliance
//    on fma_mix peephole folding (R5's VALU was ~2.4x hand count without it).
//  - Grid = 1280 blocks (5 resident/CU at 23.9KB LDS), grid-stride over the
//    2112 (b-pair, i1) slices to remove the 1.65-round dispatch tail.

#define PDIM 33
#define PP   1089
#define A_   121
#define ROWW 47              // padded row: k in [-7,39] -> p = k+7 in [0,47)
#define PADL 7
#define BLK  384
#define NV   3               // 3*384 = 1152 slots for 1089 n's
#define GRID 1280

typedef _Float16 h2v __attribute__((ext_vector_type(2)));

#if defined(__has_builtin)
#if __has_builtin(__builtin_amdgcn_fractf)
#define FRACTF(x) __builtin_amdgcn_fractf(x)
#endif
#endif
#ifndef FRACTF
#define FRACTF(x) ((x) - floorf(x))
#endif

__global__ void cs_kernel(const float* __restrict__ angles,
                          float2* __restrict__ csw, int A)
{
    int j = threadIdx.x;
    if (j < A) {
        float s, c;
        sincosf(angles[j], &s, &c);
        csw[j] = make_float2(c, s);
    }
}

__device__ __forceinline__ float fdot2u(unsigned int a, unsigned int b, float c)
{
    return __builtin_amdgcn_fdot2(__builtin_bit_cast(h2v, a),
                                  __builtin_bit_cast(h2v, b), c, false);
}

__global__ __launch_bounds__(BLK)
void fbp_adjoint_kernel(const float* __restrict__ x,
                        const float2* __restrict__ csw,     // may be null
                        const float* __restrict__ angles,   // fallback
                        float* __restrict__ out,
                        int nslice, float invA)
{
    __shared__ unsigned int dr[A_ * ROWW];   // 22.2 KB
    __shared__ float2       cs_lds[A_];

    const int t = threadIdx.x;
    const bool use_ws = (csw != nullptr);
    if (!use_ws) {
        for (int j = t; j < A_; j += BLK) {
            float s, c;
            sincosf(angles[j], &s, &c);
            cs_lds[j] = make_float2(c, s);
        }
    }

    // Per-thread n-geometry (slice-independent).
    float u0[NV], u2[NV];
#pragma unroll
    for (int nn = 0; nn < NV; ++nn) {
        int n  = t + nn * BLK;
        int nc = (n < PP) ? n : (PP - 1);
        int q0 = nc / PDIM;
        int q2 = nc - q0 * PDIM;
        u0[nn] = (float)(q0 - 16);
        u2[nn] = (float)(q2 - 16);
    }

    for (int slice = blockIdx.x; slice < nslice; slice += GRID) {
        if (slice != (int)blockIdx.x) __syncthreads();  // prev readers done

        const int hb = slice / PDIM;
        const int i1 = slice - hb * PDIM;
        const int b0 = 2 * hb;

        // Stage interleaved fp16 rows for (b0, i1) and (b0+1, i1).
        const float* r0 = x + (size_t)b0 * (A_ * PP) + (size_t)i1 * PDIM;
        const float* r1 = r0 + (size_t)(A_ * PP);
        for (int e = t; e < A_ * ROWW; e += BLK) {
            int j = e / ROWW;
            int p = e - j * ROWW;
            int k = p - PADL;
            float f0 = 0.0f, f1 = 0.0f;
            if (k >= 0 && k < PDIM) {
                size_t o = (size_t)j * PP + k;
                f0 = r0[o];
                f1 = r1[o];
            }
            dr[e] = __builtin_bit_cast(unsigned int,
                        __halves2half2(__float2half_rn(f0), __float2half_rn(f1)));
        }
        __syncthreads();

        float a0[NV] = {0.0f, 0.0f, 0.0f};
        float a1[NV] = {0.0f, 0.0f, 0.0f};

#pragma unroll 2
        for (int j = 0; j < A_; ++j) {
            float2 cj = use_ws ? csw[j] : cs_lds[j];
            const unsigned int* base = &dr[j * ROWW];
#pragma unroll
            for (int nn = 0; nn < NV; ++nn) {
                // ixp = ix + 7 in [0.37, 45.63]; kp in [0,45]
                float ixp = fmaf(u2[nn], cj.x, fmaf(u0[nn], cj.y, 23.0f));
                int   kp  = (int)ixp;
                float w1  = FRACTF(ixp);
                unsigned int wp = __builtin_bit_cast(unsigned int,
                                    __builtin_amdgcn_cvt_pkrtz(1.0f - w1, w1));
                unsigned int d0 = base[kp];        // (b0@k , b1@k )
                unsigned int d1 = base[kp + 1];    // (b0@k1, b1@k1) -> ds_read2
                unsigned int p0 = __builtin_amdgcn_perm(d1, d0, 0x05040100u); // (b0@k, b0@k1)
                unsigned int p1 = __builtin_amdgcn_perm(d1, d0, 0x07060302u); // (b1@k, b1@k1)
                a0[nn] = fdot2u(p0, wp, a0[nn]);
                a1[nn] = fdot2u(p1, wp, a1[nn]);
            }
        }

        // out[b, i0, i1, i2] = out[b*35937 + i0*1089 + i1*33 + i2]
        float* ob0 = out + (size_t)b0 * (PDIM * PP) + (size_t)i1 * PDIM;
        float* ob1 = ob0 + (size_t)(PDIM * PP);
#pragma unroll
        for (int nn = 0; nn < NV; ++nn) {
            int n = t + nn * BLK;
            if (n < PP) {
                int q0 = n / PDIM;
                int q2 = n - q0 * PDIM;
                size_t o = (size_t)q0 * PP + q2;
                ob0[o] = a0[nn] * invA;
                ob1[o] = a1[nn] * invA;
            }
        }
    }
}

extern "C" void kernel_launch(void* const* d_in, const int* in_sizes, int n_in,
                              void* d_out, int out_size, void* d_ws, size_t ws_size,
                              hipStream_t stream)
{
    const float* x      = (const float*)d_in[0];
    const float* angles = (const float*)d_in[1];
    float* out          = (float*)d_out;

    const int A = in_sizes[1];                    // 121
    const int B = in_sizes[0] / (A * PP);         // 128
    const int nslice = (B / 2) * PDIM;            // 2112

    float2* csw = nullptr;
    if (ws_size >= sizeof(float2) * (size_t)A) {
        csw = (float2*)d_ws;
        cs_kernel<<<1, 128, 0, stream>>>(angles, csw, A);
    }

    dim3 grid(GRID < nslice ? GRID : nslice);
    dim3 block(BLK);
    fbp_adjoint_kernel<<<grid, block, 0, stream>>>(x, csw, angles, out,
                                                   nslice, 1.0f / (float)A);
}